// Round 2
// baseline (561.103 us; speedup 1.0000x reference)
//
#include <hip/hip_runtime.h>
#include <stdint.h>

#define BATCH 8192

// ws byte offsets
#define OFF_W1R3    0            // uint32[96]   : w1 sign rows, 3 rows x 9 bits per word
#define OFF_W2T     1152         // uint32[1296] : w2 sign bits over ic (32), layout [k=81][oc=16]
#define OFF_W3B     6336         // uint32[648]  : w3 sign bits over ic (16) per (oc,k)
#define OFF_WLB     8928         // uint64[20]   : wl sign bits, 128 bits per oc
#define OFF_SBL     9088         // float[10]    : sign(bl)
#define OFF_TTOT    9216         // int32[81]    : layer-1 window sums (global)
#define OFF_T2      9600         // int32[16]    : layer-2 thresholds
#define OFF_S3      9664         // int64[8]     : layer-3 channel sums
#define OFF_S2PART  9728         // int32[1024*16]: per-block layer-2 partial sums
#define OFF_Z2      534528       // int16[8192*2304]
#define OFF_Z3      38283264     // int16[8192*128]
// total = 40380416 bytes (~40.4 MB)

// ---------------------------------------------------------------- K0: pack weights
__global__ __launch_bounds__(256) void k0_pack(const float* __restrict__ w1,
                                               const float* __restrict__ w2,
                                               const float* __restrict__ w3,
                                               const float* __restrict__ wl,
                                               const float* __restrict__ bl,
                                               uint8_t* __restrict__ ws) {
  uint32_t* W1R3 = (uint32_t*)(ws + OFF_W1R3);
  uint32_t* W2T  = (uint32_t*)(ws + OFF_W2T);
  uint32_t* W3B  = (uint32_t*)(ws + OFF_W3B);
  uint64_t* WLB  = (uint64_t*)(ws + OFF_WLB);
  float*    SBL  = (float*)(ws + OFF_SBL);
  int tid = threadIdx.x;
  // w1: (32,1,9,9). word i of oc holds rows 3i..3i+2 at bit offsets 0,9,18. bit=1 <=> w<0
  for (int e = tid; e < 96; e += 256) {
    int oc = e / 3, i = e % 3;
    uint32_t m = 0;
    for (int rr = 0; rr < 3; ++rr)
      for (int kw = 0; kw < 9; ++kw)
        if (w1[oc*81 + (3*i+rr)*9 + kw] < 0.f) m |= 1u << (rr*9 + kw);
    W1R3[e] = m;
  }
  // w2: (16,32,9,9) -> layout [k][oc]: 32 bits over ic
  for (int e = tid; e < 1296; e += 256) {
    int k = e >> 4, oc = e & 15;
    uint32_t m = 0;
    for (int ic = 0; ic < 32; ++ic)
      if (w2[(oc*32 + ic)*81 + k] < 0.f) m |= 1u << ic;
    W2T[e] = m;
  }
  // w3: (8,16,9,9)
  for (int e = tid; e < 648; e += 256) {
    int oc = e / 81, k = e % 81;
    uint32_t m = 0;
    for (int ic = 0; ic < 16; ++ic)
      if (w3[(oc*16 + ic)*81 + k] < 0.f) m |= 1u << ic;
    W3B[e] = m;
  }
  // wl: (10,8,4,4) -> 128 bits per oc, bit j = ic*16 + (y*4+x)
  for (int e = tid; e < 20; e += 256) {
    int oc = e >> 1, word = e & 1;
    uint64_t m = 0;
    for (int b = 0; b < 64; ++b)
      if (wl[oc*128 + word*64 + b] < 0.f) m |= 1ull << b;
    WLB[e] = m;
  }
  if (tid < 10) SBL[tid] = (bl[tid] >= 0.f) ? 1.f : -1.f;
}

// ---------------------------------------------------------------- K1: layer-1 window sums
__global__ __launch_bounds__(256) void k1_tsum(const float* __restrict__ x,
                                               uint8_t* __restrict__ ws) {
  int* Ttot = (int*)(ws + OFF_TTOT);
  __shared__ uint16_t RP[4][28][29];
  __shared__ uint16_t P[4][29][29];
  __shared__ int Tacc[81];
  const int tid = threadIdx.x;
  const int wv = tid >> 6, ln = tid & 63;
  if (tid < 81) Tacc[tid] = 0;
  __syncthreads();
  for (int it = 0; it < 8; ++it) {
    int img = blockIdx.x * 32 + it * 4 + wv;
    const float* xi = x + (size_t)img * 784;
    if (ln < 28) {
      uint16_t cnt = 0;
      RP[wv][ln][0] = 0;
      for (int c = 0; c < 28; ++c) {
        cnt += (xi[ln*28 + c] < 0.f) ? 1 : 0;
        RP[wv][ln][c+1] = cnt;
      }
    }
    __syncthreads();
    if (ln < 29) {
      uint16_t run = 0;
      P[wv][0][ln] = 0;
      for (int i = 1; i <= 28; ++i) {
        run += RP[wv][i-1][ln];
        P[wv][i][ln] = run;
      }
    }
    __syncthreads();
    if (ln < 81) {
      int kh = ln / 9, kw = ln % 9;
      int cnt = (int)P[wv][kh+20][kw+20] - (int)P[wv][kh][kw+20]
              - (int)P[wv][kh+20][kw]  + (int)P[wv][kh][kw];
      atomicAdd(&Tacc[ln], 400 - 2*cnt);
    }
    __syncthreads();
  }
  if (tid < 81) atomicAdd(&Ttot[tid], Tacc[tid]);
}

// ---------------------------------------------------------------- K2: conv1 (recompute) + conv2
#define K2_IMGS 8
__global__ __launch_bounds__(256, 4) void k2_conv12(const float* __restrict__ x,
                                                    uint8_t* __restrict__ ws) {
  const uint32_t* W1R3g = (const uint32_t*)(ws + OFF_W1R3);
  const uint32_t* W2Tg  = (const uint32_t*)(ws + OFF_W2T);
  const int* Ttot = (const int*)(ws + OFF_TTOT);
  int* S2P = (int*)(ws + OFF_S2PART);

  __shared__ uint32_t __attribute__((aligned(16))) rowm[K2_IMGS*28];
  __shared__ uint32_t __attribute__((aligned(16))) w1r3[96];
  __shared__ uint32_t __attribute__((aligned(16))) w2t[1296];
  __shared__ int tlds[81];
  __shared__ int t1s[32];
  __shared__ uint32_t __attribute__((aligned(16))) A1s[K2_IMGS*400];
  __shared__ int s2acc[16];

  const int tid = threadIdx.x;
  const int img0 = blockIdx.x * K2_IMGS;

  for (int e = tid; e < 96; e += 256)   w1r3[e] = W1R3g[e];
  for (int e = tid; e < 1296; e += 256) w2t[e]  = W2Tg[e];
  if (tid < 81) tlds[tid] = Ttot[tid];
  if (tid < 16) s2acc[tid] = 0;
  if (tid < K2_IMGS*28) {
    int il = tid / 28, rr = tid % 28;
    const float4* xr = (const float4*)(x + (size_t)(img0 + il) * 784 + rr * 28);
    uint32_t m = 0;
    #pragma unroll
    for (int j = 0; j < 7; ++j) {
      float4 v = xr[j];
      if (v.x < 0.f) m |= 1u << (j*4+0);
      if (v.y < 0.f) m |= 1u << (j*4+1);
      if (v.z < 0.f) m |= 1u << (j*4+2);
      if (v.w < 0.f) m |= 1u << (j*4+3);
    }
    rowm[tid] = m;
  }
  __syncthreads();

  // layer-1 thresholds (odd parity): t1 = smallest odd integer >= S1/N1
  if (tid < 32) {
    long long S = 0;
    for (int kh = 0; kh < 9; ++kh)
      for (int kw = 0; kw < 9; ++kw) {
        int bit = (w1r3[tid*3 + kh/3] >> ((kh%3)*9 + kw)) & 1;
        S += (long long)(1 - 2*bit) * tlds[kh*9 + kw];
      }
    const long long N1 = (long long)BATCH * 400;
    long long q = S / N1, rr = S % N1;
    long long t = q + (rr > 0 ? 1 : 0);
    if ((t & 1) == 0) t += 1;
    t1s[tid] = (int)t;
  }
  __syncthreads();

  // conv1 + binarize -> A1s. Task = (il, oh, 5-ow group): 8*20*4 = 640 tasks.
  for (int G = tid; G < K2_IMGS*80; G += 256) {
    int il = G / 80, rem = G - il*80;
    int oh = rem >> 2, ow0 = (rem & 3) * 5;
    uint32_t R[9];
    #pragma unroll
    for (int i = 0; i < 9; ++i) R[i] = rowm[il*28 + oh + i];
    uint32_t win[5][3];
    #pragma unroll
    for (int j = 0; j < 5; ++j) {
      int ow = ow0 + j;
      #pragma unroll
      for (int i = 0; i < 3; ++i) {
        uint32_t b0 = (R[3*i]   >> ow) & 0x1FFu;
        uint32_t b1 = (R[3*i+1] >> ow) & 0x1FFu;
        uint32_t b2 = (R[3*i+2] >> ow) & 0x1FFu;
        win[j][i] = b0 | (b1 << 9) | (b2 << 18);
      }
    }
    uint32_t mask[5] = {0,0,0,0,0};
    #pragma unroll
    for (int ocg = 0; ocg < 4; ++ocg) {
      const uint4* wp = (const uint4*)&w1r3[ocg*24];
      uint32_t wr[24];
      #pragma unroll
      for (int q = 0; q < 6; ++q) {
        uint4 v = wp[q];
        wr[q*4+0]=v.x; wr[q*4+1]=v.y; wr[q*4+2]=v.z; wr[q*4+3]=v.w;
      }
      #pragma unroll
      for (int o8 = 0; o8 < 8; ++o8) {
        int oc = ocg*8 + o8;
        int t = t1s[oc];
        #pragma unroll
        for (int j = 0; j < 5; ++j) {
          int mm = __popc(win[j][0] ^ wr[o8*3])
                 + __popc(win[j][1] ^ wr[o8*3+1])
                 + __popc(win[j][2] ^ wr[o8*3+2]);
          mask[j] |= (uint32_t)((81 - 2*mm) < t) << oc;
        }
      }
    }
    #pragma unroll
    for (int j = 0; j < 5; ++j) A1s[il*400 + oh*20 + ow0 + j] = mask[j];
  }
  __syncthreads();

  // conv2: task = (il, oy, oc-pair): 8*12*8 = 768 tasks, 3 per thread.
  // och = G&7 is invariant per thread (256 % 8 == 0) -> accumulate channel sums in regs.
  uint32_t* Z2w = (uint32_t*)(ws + OFF_Z2);
  const int och = tid & 7, oc0 = och << 1;
  int sl0 = 0, sl1 = 0;
  for (int r = 0; r < 3; ++r) {
    int G = tid + r*256;
    int il = G / 96, rem = G - il*96;
    int oy = rem >> 3;
    const uint32_t* A = &A1s[il*400 + oy*20];
    int acc0[12], acc1[12];
    #pragma unroll
    for (int p = 0; p < 12; ++p) { acc0[p] = 0; acc1[p] = 0; }
    for (int kh = 0; kh < 9; ++kh) {
      const uint4* ar = (const uint4*)(A + kh*20);
      uint32_t a[20];
      #pragma unroll
      for (int q = 0; q < 5; ++q) {
        uint4 v = ar[q];
        a[q*4+0]=v.x; a[q*4+1]=v.y; a[q*4+2]=v.z; a[q*4+3]=v.w;
      }
      uint32_t wv0[9], wv1[9];
      #pragma unroll
      for (int kw = 0; kw < 9; ++kw) {
        uint2 wv = *(const uint2*)&w2t[(kh*9 + kw)*16 + oc0];
        wv0[kw] = wv.x; wv1[kw] = wv.y;
      }
      #pragma unroll
      for (int kw = 0; kw < 9; ++kw) {
        #pragma unroll
        for (int px = 0; px < 12; ++px) {
          acc0[px] += __popc(a[kw+px] ^ wv0[kw]);
          acc1[px] += __popc(a[kw+px] ^ wv1[kw]);
        }
      }
    }
    // pack + store rows (12 int16 per oc), sum for channel means
    size_t base0 = (size_t)(img0+il)*1152 + (size_t)oc0*72 + oy*6;  // uint32 index
    uint32_t u0[6], u1[6];
    #pragma unroll
    for (int h2 = 0; h2 < 6; ++h2) {
      int za = 2592 - 2*acc0[2*h2], zb = 2592 - 2*acc0[2*h2+1];
      sl0 += za + zb;
      u0[h2] = (uint32_t)(uint16_t)(int16_t)za | ((uint32_t)(uint16_t)(int16_t)zb << 16);
      int zc = 2592 - 2*acc1[2*h2], zd = 2592 - 2*acc1[2*h2+1];
      sl1 += zc + zd;
      u1[h2] = (uint32_t)(uint16_t)(int16_t)zc | ((uint32_t)(uint16_t)(int16_t)zd << 16);
    }
    uint2* p0 = (uint2*)(Z2w + base0);
    p0[0] = make_uint2(u0[0], u0[1]); p0[1] = make_uint2(u0[2], u0[3]); p0[2] = make_uint2(u0[4], u0[5]);
    uint2* p1 = (uint2*)(Z2w + base0 + 72);
    p1[0] = make_uint2(u1[0], u1[1]); p1[1] = make_uint2(u1[2], u1[3]); p1[2] = make_uint2(u1[4], u1[5]);
  }
  atomicAdd(&s2acc[oc0],   sl0);
  atomicAdd(&s2acc[oc0+1], sl1);
  __syncthreads();
  if (tid < 16) S2P[blockIdx.x*16 + tid] = s2acc[tid];
}

// ---------------------------------------------------------------- K2b: reduce S2 partials -> t2
__global__ __launch_bounds__(256) void k2b_reduce(uint8_t* __restrict__ ws) {
  const int* S2P = (const int*)(ws + OFF_S2PART);
  int* T2 = (int*)(ws + OFF_T2);
  __shared__ long long part[256];
  int tid = threadIdx.x;
  int c = tid & 15, g = tid >> 4;  // 16 groups over 1024 blocks
  long long s = 0;
  for (int b = g*64; b < g*64 + 64; ++b) s += S2P[b*16 + c];
  part[tid] = s;
  __syncthreads();
  if (tid < 16) {
    long long S = 0;
    for (int g2 = 0; g2 < 16; ++g2) S += part[g2*16 + tid];
    const long long N2 = (long long)BATCH * 144;
    long long q = S / N2, r = S % N2;
    long long t = q + (r > 0 ? 1 : 0);
    if (t & 1) t += 1;   // z2 is even
    T2[tid] = (int)t;
  }
}

// ---------------------------------------------------------------- K3: conv3
__global__ __launch_bounds__(256) void k3_conv3(uint8_t* __restrict__ ws) {
  const int16_t* Z2 = (const int16_t*)(ws + OFF_Z2);
  const int* T2 = (const int*)(ws + OFF_T2);
  const uint32_t* W3Bg = (const uint32_t*)(ws + OFF_W3B);
  int16_t* Z3 = (int16_t*)(ws + OFF_Z3);
  unsigned long long* S3 = (unsigned long long*)(ws + OFF_S3);

  __shared__ uint32_t w3b[648];
  __shared__ int t2[16];
  __shared__ uint32_t A2[2][144];
  __shared__ int s3acc[8];

  const int tid = threadIdx.x;
  for (int e = tid; e < 648; e += 256) w3b[e] = W3Bg[e];
  if (tid < 16) t2[tid] = T2[tid];
  if (tid < 8) s3acc[tid] = 0;
  __syncthreads();

  const int half = tid >> 7, h = tid & 127;
  for (int it = 0; it < 8; ++it) {
    int img = blockIdx.x * 16 + it*2 + half;
    const int16_t* z2i = Z2 + (size_t)img * 2304;
    for (int p = h; p < 144; p += 128) {
      uint32_t m = 0;
      #pragma unroll
      for (int ic = 0; ic < 16; ++ic)
        if ((int)z2i[ic*144 + p] < t2[ic]) m |= 1u << ic;
      A2[half][p] = m;
    }
    __syncthreads();
    {
      int oc = h >> 4, pix = h & 15;
      int oy = pix >> 2, ox = pix & 3;
      int mism = 0;
      for (int kh = 0; kh < 9; ++kh)
        #pragma unroll
        for (int kw = 0; kw < 9; ++kw)
          mism += __popc(A2[half][(oy+kh)*12 + ox + kw] ^ w3b[oc*81 + kh*9 + kw]);
      int z3 = 1296 - 2*mism;
      Z3[(size_t)img*128 + h] = (int16_t)z3;
      atomicAdd(&s3acc[oc], z3);
    }
    __syncthreads();
  }
  if (tid < 8)
    atomicAdd(&S3[tid], (unsigned long long)(long long)s3acc[tid]);
}

// ---------------------------------------------------------------- K4: conv4 + bias -> out
__global__ __launch_bounds__(256) void k4_final(uint8_t* __restrict__ ws,
                                                float* __restrict__ out) {
  const int16_t* Z3 = (const int16_t*)(ws + OFF_Z3);
  const long long* S3 = (const long long*)(ws + OFF_S3);
  const uint64_t* WLBg = (const uint64_t*)(ws + OFF_WLB);
  const float* SBLg = (const float*)(ws + OFF_SBL);
  __shared__ int t3[8];
  __shared__ uint64_t wlb[20];
  __shared__ float sbl[10];
  const int tid = threadIdx.x;
  if (tid < 8) {
    long long S = S3[tid];
    const long long N3 = (long long)BATCH * 16;
    long long q = S / N3, r = S % N3;
    long long t = q + (r > 0 ? 1 : 0);
    if (t & 1) t += 1;   // z3 is even
    t3[tid] = (int)t;
  }
  if (tid < 20) wlb[tid] = WLBg[tid];
  if (tid < 10) sbl[tid] = SBLg[tid];
  __syncthreads();
  int img = blockIdx.x * 256 + tid;
  const int16_t* z3i = Z3 + (size_t)img * 128;
  uint64_t a0 = 0, a1 = 0;
  for (int j = 0; j < 64; ++j)
    if ((int)z3i[j] < t3[j >> 4]) a0 |= 1ull << j;
  for (int j = 0; j < 64; ++j)
    if ((int)z3i[64 + j] < t3[(64 + j) >> 4]) a1 |= 1ull << j;
  #pragma unroll
  for (int oc = 0; oc < 10; ++oc) {
    int mism = __popcll(a0 ^ wlb[oc*2]) + __popcll(a1 ^ wlb[oc*2 + 1]);
    out[(size_t)img*10 + oc] = (float)(128 - 2*mism) + sbl[oc];
  }
}

// ----------------------------------------------------------------
extern "C" void kernel_launch(void* const* d_in, const int* in_sizes, int n_in,
                              void* d_out, int out_size, void* d_ws, size_t ws_size,
                              hipStream_t stream) {
  (void)in_sizes; (void)n_in; (void)out_size; (void)ws_size;
  const float* x  = (const float*)d_in[0];
  const float* w1 = (const float*)d_in[1];
  // d_in[2] = b1, d_in[4] = b2, d_in[6] = b3: biases cancel under BN -> unused
  const float* w2 = (const float*)d_in[3];
  const float* w3 = (const float*)d_in[5];
  const float* wl = (const float*)d_in[7];
  const float* bl = (const float*)d_in[8];
  uint8_t* ws = (uint8_t*)d_ws;
  float* out = (float*)d_out;

  // zero T_total / T2 / S3 accumulator region (ws is poisoned 0xAA each call)
  hipMemsetAsync(ws + OFF_TTOT, 0, 512, stream);
  k0_pack<<<1, 256, 0, stream>>>(w1, w2, w3, wl, bl, ws);
  k1_tsum<<<256, 256, 0, stream>>>(x, ws);
  k2_conv12<<<1024, 256, 0, stream>>>(x, ws);
  k2b_reduce<<<1, 256, 0, stream>>>(ws);
  k3_conv3<<<512, 256, 0, stream>>>(ws);
  k4_final<<<32, 256, 0, stream>>>(ws, out);
}

// Round 3
// 301.517 us; speedup vs baseline: 1.8609x; 1.8609x over previous
//
#include <hip/hip_runtime.h>
#include <stdint.h>

#define BATCH 8192

// ws byte offsets
#define OFF_W1R3    0            // uint32[96]   : w1 sign rows, 3 rows x 9 bits per word
#define OFF_W2T     1152         // uint32[1296] : w2 sign bits over ic (32), layout [k=81][oc=16]
#define OFF_W3B     6336         // uint32[648]  : w3 sign bits over ic (16) per (oc,k)
#define OFF_WLB     8928         // uint64[20]   : wl sign bits, 128 bits per oc
#define OFF_SBL     9088         // float[10]    : sign(bl)
#define OFF_TTOT    9216         // int32[81]    : layer-1 window sums (global)
#define OFF_T2      9600         // int32[16]    : layer-2 thresholds
#define OFF_S3      9664         // int64[8]     : layer-3 channel sums
#define OFF_S2PART  9728         // int32[1024*16]: per-block layer-2 partial sums
#define OFF_Z2      534528       // int16[8192*2304]
#define OFF_Z3      38283264     // int16[8192*128]
// total = 40380416 bytes (~40.4 MB)

// ---------------------------------------------------------------- K0: pack weights
__global__ __launch_bounds__(256) void k0_pack(const float* __restrict__ w1,
                                               const float* __restrict__ w2,
                                               const float* __restrict__ w3,
                                               const float* __restrict__ wl,
                                               const float* __restrict__ bl,
                                               uint8_t* __restrict__ ws) {
  uint32_t* W1R3 = (uint32_t*)(ws + OFF_W1R3);
  uint32_t* W2T  = (uint32_t*)(ws + OFF_W2T);
  uint32_t* W3B  = (uint32_t*)(ws + OFF_W3B);
  uint64_t* WLB  = (uint64_t*)(ws + OFF_WLB);
  float*    SBL  = (float*)(ws + OFF_SBL);
  int tid = threadIdx.x;
  // w1: (32,1,9,9). word i of oc holds rows 3i..3i+2 at bit offsets 0,9,18. bit=1 <=> w<0
  for (int e = tid; e < 96; e += 256) {
    int oc = e / 3, i = e % 3;
    uint32_t m = 0;
    for (int rr = 0; rr < 3; ++rr)
      for (int kw = 0; kw < 9; ++kw)
        if (w1[oc*81 + (3*i+rr)*9 + kw] < 0.f) m |= 1u << (rr*9 + kw);
    W1R3[e] = m;
  }
  // w2: (16,32,9,9) -> layout [k][oc]: 32 bits over ic
  for (int e = tid; e < 1296; e += 256) {
    int k = e >> 4, oc = e & 15;
    uint32_t m = 0;
    for (int ic = 0; ic < 32; ++ic)
      if (w2[(oc*32 + ic)*81 + k] < 0.f) m |= 1u << ic;
    W2T[e] = m;
  }
  // w3: (8,16,9,9)
  for (int e = tid; e < 648; e += 256) {
    int oc = e / 81, k = e % 81;
    uint32_t m = 0;
    for (int ic = 0; ic < 16; ++ic)
      if (w3[(oc*16 + ic)*81 + k] < 0.f) m |= 1u << ic;
    W3B[e] = m;
  }
  // wl: (10,8,4,4) -> 128 bits per oc, bit j = ic*16 + (y*4+x)
  for (int e = tid; e < 20; e += 256) {
    int oc = e >> 1, word = e & 1;
    uint64_t m = 0;
    for (int b = 0; b < 64; ++b)
      if (wl[oc*128 + word*64 + b] < 0.f) m |= 1ull << b;
    WLB[e] = m;
  }
  if (tid < 10) SBL[tid] = (bl[tid] >= 0.f) ? 1.f : -1.f;
}

// ---------------------------------------------------------------- K1: layer-1 window sums
// grid 1024, 8 images/block, wave per image, 2 iterations.
__global__ __launch_bounds__(256) void k1_tsum(const float* __restrict__ x,
                                               uint8_t* __restrict__ ws) {
  int* Ttot = (int*)(ws + OFF_TTOT);
  __shared__ uint16_t RP[4][28][29];
  __shared__ uint16_t P[4][29][29];
  __shared__ int Tacc[81];
  const int tid = threadIdx.x;
  const int wv = tid >> 6, ln = tid & 63;
  if (tid < 81) Tacc[tid] = 0;
  __syncthreads();
  for (int it = 0; it < 2; ++it) {
    int img = blockIdx.x * 8 + it * 4 + wv;
    const float* xi = x + (size_t)img * 784;
    if (ln < 28) {
      uint16_t cnt = 0;
      RP[wv][ln][0] = 0;
      for (int c = 0; c < 28; ++c) {
        cnt += (xi[ln*28 + c] < 0.f) ? 1 : 0;
        RP[wv][ln][c+1] = cnt;
      }
    }
    __syncthreads();
    if (ln < 29) {
      uint16_t run = 0;
      P[wv][0][ln] = 0;
      for (int i = 1; i <= 28; ++i) {
        run += RP[wv][i-1][ln];
        P[wv][i][ln] = run;
      }
    }
    __syncthreads();
    if (ln < 81) {
      int kh = ln / 9, kw = ln % 9;
      int cnt = (int)P[wv][kh+20][kw+20] - (int)P[wv][kh][kw+20]
              - (int)P[wv][kh+20][kw]  + (int)P[wv][kh][kw];
      atomicAdd(&Tacc[ln], 400 - 2*cnt);
    }
    __syncthreads();
  }
  if (tid < 81) atomicAdd(&Ttot[tid], Tacc[tid]);
}

// ---------------------------------------------------------------- K2: conv1 (recompute) + conv2
#define K2_IMGS 8
__global__ __launch_bounds__(256) void k2_conv12(const float* __restrict__ x,
                                                 uint8_t* __restrict__ ws) {
  const uint32_t* W1R3g = (const uint32_t*)(ws + OFF_W1R3);
  const uint32_t* W2Tg  = (const uint32_t*)(ws + OFF_W2T);
  const int* Ttot = (const int*)(ws + OFF_TTOT);
  int* S2P = (int*)(ws + OFF_S2PART);

  __shared__ uint32_t __attribute__((aligned(16))) rowm[K2_IMGS*28];
  __shared__ uint32_t __attribute__((aligned(16))) w1r3[96];
  __shared__ uint32_t __attribute__((aligned(16))) w2t[1296];
  __shared__ int tlds[81];
  __shared__ int t1s[32];
  __shared__ uint32_t __attribute__((aligned(16))) A1s[K2_IMGS*400];
  __shared__ int s2acc[16];

  const int tid = threadIdx.x;
  const int img0 = blockIdx.x * K2_IMGS;

  for (int e = tid; e < 96; e += 256)   w1r3[e] = W1R3g[e];
  for (int e = tid; e < 1296; e += 256) w2t[e]  = W2Tg[e];
  if (tid < 81) tlds[tid] = Ttot[tid];
  if (tid < 16) s2acc[tid] = 0;
  if (tid < K2_IMGS*28) {
    int il = tid / 28, rr = tid % 28;
    const float4* xr = (const float4*)(x + (size_t)(img0 + il) * 784 + rr * 28);
    uint32_t m = 0;
    #pragma unroll
    for (int j = 0; j < 7; ++j) {
      float4 v = xr[j];
      if (v.x < 0.f) m |= 1u << (j*4+0);
      if (v.y < 0.f) m |= 1u << (j*4+1);
      if (v.z < 0.f) m |= 1u << (j*4+2);
      if (v.w < 0.f) m |= 1u << (j*4+3);
    }
    rowm[tid] = m;
  }
  __syncthreads();

  // layer-1 thresholds (odd parity): t1 = smallest odd integer >= S1/N1
  if (tid < 32) {
    long long S = 0;
    for (int kh = 0; kh < 9; ++kh)
      for (int kw = 0; kw < 9; ++kw) {
        int bit = (w1r3[tid*3 + kh/3] >> ((kh%3)*9 + kw)) & 1;
        S += (long long)(1 - 2*bit) * tlds[kh*9 + kw];
      }
    const long long N1 = (long long)BATCH * 400;
    long long q = S / N1, rr = S % N1;
    long long t = q + (rr > 0 ? 1 : 0);
    if ((t & 1) == 0) t += 1;
    t1s[tid] = (int)t;
  }
  __syncthreads();

  // conv1 + binarize -> A1s. Task = (il, oh, 5-ow group): 8*20*4 = 640 tasks.
  for (int G = tid; G < K2_IMGS*80; G += 256) {
    int il = G / 80, rem = G - il*80;
    int oh = rem >> 2, ow0 = (rem & 3) * 5;
    uint32_t R[9];
    #pragma unroll
    for (int i = 0; i < 9; ++i) R[i] = rowm[il*28 + oh + i];
    uint32_t win[5][3];
    #pragma unroll
    for (int j = 0; j < 5; ++j) {
      int ow = ow0 + j;
      #pragma unroll
      for (int i = 0; i < 3; ++i) {
        uint32_t b0 = (R[3*i]   >> ow) & 0x1FFu;
        uint32_t b1 = (R[3*i+1] >> ow) & 0x1FFu;
        uint32_t b2 = (R[3*i+2] >> ow) & 0x1FFu;
        win[j][i] = b0 | (b1 << 9) | (b2 << 18);
      }
    }
    uint32_t mask[5] = {0,0,0,0,0};
    #pragma unroll
    for (int ocg = 0; ocg < 4; ++ocg) {
      const uint4* wp = (const uint4*)&w1r3[ocg*24];
      uint32_t wr[24];
      #pragma unroll
      for (int q = 0; q < 6; ++q) {
        uint4 v = wp[q];
        wr[q*4+0]=v.x; wr[q*4+1]=v.y; wr[q*4+2]=v.z; wr[q*4+3]=v.w;
      }
      #pragma unroll
      for (int o8 = 0; o8 < 8; ++o8) {
        int oc = ocg*8 + o8;
        int t = t1s[oc];
        #pragma unroll
        for (int j = 0; j < 5; ++j) {
          int mm = __popc(win[j][0] ^ wr[o8*3])
                 + __popc(win[j][1] ^ wr[o8*3+1])
                 + __popc(win[j][2] ^ wr[o8*3+2]);
          mask[j] |= (uint32_t)((81 - 2*mm) < t) << oc;
        }
      }
    }
    #pragma unroll
    for (int j = 0; j < 5; ++j) A1s[il*400 + oh*20 + ow0 + j] = mask[j];
  }
  __syncthreads();

  // conv2: task = (il, oy, oc-pair): 8*12*8 = 768 tasks, 3 per thread.
  // och = tid&7 is invariant per thread (256 % 8 == 0) -> channel sums in regs.
  uint32_t* Z2w = (uint32_t*)(ws + OFF_Z2);
  const int och = tid & 7, oc0 = och << 1;
  int sl0 = 0, sl1 = 0;
  for (int r = 0; r < 3; ++r) {
    int G = tid + r*256;
    int il = G / 96, rem = G - il*96;
    int oy = rem >> 3;
    const uint32_t* A = &A1s[il*400 + oy*20];
    int acc0[12], acc1[12];
    #pragma unroll
    for (int p = 0; p < 12; ++p) { acc0[p] = 0; acc1[p] = 0; }
    for (int kh = 0; kh < 9; ++kh) {
      const uint4* ar = (const uint4*)(A + kh*20);
      uint32_t a[20];
      #pragma unroll
      for (int q = 0; q < 5; ++q) {
        uint4 v = ar[q];
        a[q*4+0]=v.x; a[q*4+1]=v.y; a[q*4+2]=v.z; a[q*4+3]=v.w;
      }
      uint32_t wv0[9], wv1[9];
      #pragma unroll
      for (int kw = 0; kw < 9; ++kw) {
        uint2 wv = *(const uint2*)&w2t[(kh*9 + kw)*16 + oc0];
        wv0[kw] = wv.x; wv1[kw] = wv.y;
      }
      #pragma unroll
      for (int kw = 0; kw < 9; ++kw) {
        #pragma unroll
        for (int px = 0; px < 12; ++px) {
          acc0[px] += __popc(a[kw+px] ^ wv0[kw]);
          acc1[px] += __popc(a[kw+px] ^ wv1[kw]);
        }
      }
    }
    // pack + store rows (12 int16 per oc), sum for channel means
    size_t base0 = (size_t)(img0+il)*1152 + (size_t)oc0*72 + oy*6;  // uint32 index
    uint32_t u0[6], u1[6];
    #pragma unroll
    for (int h2 = 0; h2 < 6; ++h2) {
      int za = 2592 - 2*acc0[2*h2], zb = 2592 - 2*acc0[2*h2+1];
      sl0 += za + zb;
      u0[h2] = (uint32_t)(uint16_t)(int16_t)za | ((uint32_t)(uint16_t)(int16_t)zb << 16);
      int zc = 2592 - 2*acc1[2*h2], zd = 2592 - 2*acc1[2*h2+1];
      sl1 += zc + zd;
      u1[h2] = (uint32_t)(uint16_t)(int16_t)zc | ((uint32_t)(uint16_t)(int16_t)zd << 16);
    }
    uint2* p0 = (uint2*)(Z2w + base0);
    p0[0] = make_uint2(u0[0], u0[1]); p0[1] = make_uint2(u0[2], u0[3]); p0[2] = make_uint2(u0[4], u0[5]);
    uint2* p1 = (uint2*)(Z2w + base0 + 72);
    p1[0] = make_uint2(u1[0], u1[1]); p1[1] = make_uint2(u1[2], u1[3]); p1[2] = make_uint2(u1[4], u1[5]);
  }
  atomicAdd(&s2acc[oc0],   sl0);
  atomicAdd(&s2acc[oc0+1], sl1);
  __syncthreads();
  if (tid < 16) S2P[blockIdx.x*16 + tid] = s2acc[tid];
}

// ---------------------------------------------------------------- K2b: reduce S2 partials -> t2
__global__ __launch_bounds__(256) void k2b_reduce(uint8_t* __restrict__ ws) {
  const int* S2P = (const int*)(ws + OFF_S2PART);
  int* T2 = (int*)(ws + OFF_T2);
  __shared__ long long part[256];
  int tid = threadIdx.x;
  int c = tid & 15, g = tid >> 4;  // 16 groups over 1024 blocks
  long long s = 0;
  for (int b = g*64; b < g*64 + 64; ++b) s += S2P[b*16 + c];
  part[tid] = s;
  __syncthreads();
  if (tid < 16) {
    long long S = 0;
    for (int g2 = 0; g2 < 16; ++g2) S += part[g2*16 + tid];
    const long long N2 = (long long)BATCH * 144;
    long long q = S / N2, r = S % N2;
    long long t = q + (r > 0 ? 1 : 0);
    if (t & 1) t += 1;   // z2 is even
    T2[tid] = (int)t;
  }
}

// ---------------------------------------------------------------- K3: conv3 (grid 1024, 8 imgs/block)
__global__ __launch_bounds__(256) void k3_conv3(uint8_t* __restrict__ ws) {
  const int16_t* Z2 = (const int16_t*)(ws + OFF_Z2);
  const int* T2 = (const int*)(ws + OFF_T2);
  const uint32_t* W3Bg = (const uint32_t*)(ws + OFF_W3B);
  int16_t* Z3 = (int16_t*)(ws + OFF_Z3);
  unsigned long long* S3 = (unsigned long long*)(ws + OFF_S3);

  __shared__ uint32_t w3b[648];
  __shared__ int t2[16];
  __shared__ uint32_t A2[2][144];
  __shared__ int s3acc[8];

  const int tid = threadIdx.x;
  for (int e = tid; e < 648; e += 256) w3b[e] = W3Bg[e];
  if (tid < 16) t2[tid] = T2[tid];
  if (tid < 8) s3acc[tid] = 0;
  __syncthreads();

  const int half = tid >> 7, h = tid & 127;
  for (int it = 0; it < 4; ++it) {
    int img = blockIdx.x * 8 + it*2 + half;
    const int16_t* z2i = Z2 + (size_t)img * 2304;
    for (int p = h; p < 144; p += 128) {
      uint32_t m = 0;
      #pragma unroll
      for (int ic = 0; ic < 16; ++ic)
        if ((int)z2i[ic*144 + p] < t2[ic]) m |= 1u << ic;
      A2[half][p] = m;
    }
    __syncthreads();
    {
      int oc = h >> 4, pix = h & 15;
      int oy = pix >> 2, ox = pix & 3;
      int mism = 0;
      for (int kh = 0; kh < 9; ++kh)
        #pragma unroll
        for (int kw = 0; kw < 9; ++kw)
          mism += __popc(A2[half][(oy+kh)*12 + ox + kw] ^ w3b[oc*81 + kh*9 + kw]);
      int z3 = 1296 - 2*mism;
      Z3[(size_t)img*128 + h] = (int16_t)z3;
      atomicAdd(&s3acc[oc], z3);
    }
    __syncthreads();
  }
  if (tid < 8)
    atomicAdd(&S3[tid], (unsigned long long)(long long)s3acc[tid]);
}

// ---------------------------------------------------------------- K4: conv4 + bias -> out
__global__ __launch_bounds__(256) void k4_final(uint8_t* __restrict__ ws,
                                               float* __restrict__ out) {
  const int16_t* Z3 = (const int16_t*)(ws + OFF_Z3);
  const long long* S3 = (const long long*)(ws + OFF_S3);
  const uint64_t* WLBg = (const uint64_t*)(ws + OFF_WLB);
  const float* SBLg = (const float*)(ws + OFF_SBL);
  __shared__ int t3[8];
  __shared__ uint64_t wlb[20];
  __shared__ float sbl[10];
  const int tid = threadIdx.x;
  if (tid < 8) {
    long long S = S3[tid];
    const long long N3 = (long long)BATCH * 16;
    long long q = S / N3, r = S % N3;
    long long t = q + (r > 0 ? 1 : 0);
    if (t & 1) t += 1;   // z3 is even
    t3[tid] = (int)t;
  }
  if (tid < 20) wlb[tid] = WLBg[tid];
  if (tid < 10) sbl[tid] = SBLg[tid];
  __syncthreads();
  int img = blockIdx.x * 256 + tid;
  const int16_t* z3i = Z3 + (size_t)img * 128;
  uint64_t a0 = 0, a1 = 0;
  for (int j = 0; j < 64; ++j)
    if ((int)z3i[j] < t3[j >> 4]) a0 |= 1ull << j;
  for (int j = 0; j < 64; ++j)
    if ((int)z3i[64 + j] < t3[(64 + j) >> 4]) a1 |= 1ull << j;
  #pragma unroll
  for (int oc = 0; oc < 10; ++oc) {
    int mism = __popcll(a0 ^ wlb[oc*2]) + __popcll(a1 ^ wlb[oc*2 + 1]);
    out[(size_t)img*10 + oc] = (float)(128 - 2*mism) + sbl[oc];
  }
}

// ----------------------------------------------------------------
extern "C" void kernel_launch(void* const* d_in, const int* in_sizes, int n_in,
                              void* d_out, int out_size, void* d_ws, size_t ws_size,
                              hipStream_t stream) {
  (void)in_sizes; (void)n_in; (void)out_size; (void)ws_size;
  const float* x  = (const float*)d_in[0];
  const float* w1 = (const float*)d_in[1];
  // d_in[2] = b1, d_in[4] = b2, d_in[6] = b3: biases cancel under BN -> unused
  const float* w2 = (const float*)d_in[3];
  const float* w3 = (const float*)d_in[5];
  const float* wl = (const float*)d_in[7];
  const float* bl = (const float*)d_in[8];
  uint8_t* ws = (uint8_t*)d_ws;
  float* out = (float*)d_out;

  // zero T_total / T2 / S3 accumulator region (ws is poisoned 0xAA each call)
  hipMemsetAsync(ws + OFF_TTOT, 0, 512, stream);
  k0_pack<<<1, 256, 0, stream>>>(w1, w2, w3, wl, bl, ws);
  k1_tsum<<<1024, 256, 0, stream>>>(x, ws);
  k2_conv12<<<1024, 256, 0, stream>>>(x, ws);
  k2b_reduce<<<1, 256, 0, stream>>>(ws);
  k3_conv3<<<1024, 256, 0, stream>>>(ws);
  k4_final<<<32, 256, 0, stream>>>(ws, out);
}

// Round 5
// 257.808 us; speedup vs baseline: 2.1764x; 1.1695x over previous
//
#include <hip/hip_runtime.h>
#include <stdint.h>

#define BATCH 8192

// ws byte offsets
#define OFF_W1R3   0         // uint32[96]  : w1 sign rows, 3 rows x 9 bits per word
#define OFF_W2P    384       // uint32[1440]: w2 signs, [och 8][kh 9][kw 10(pad)] x uint2 (oc-pair)
#define OFF_W3P    6144      // uint32[864] : w3 signs, [oc 8][kh 9][kw 12(pad)]
#define OFF_WLB    9600      // uint64[20]  : wl sign bits, 128 bits per oc
#define OFF_SBL    9760      // float[10]   : sign(bl)
#define OFF_TTOT   9856      // int32[81]   : layer-1 window sums (global, atomic)
#define OFF_S3     10184     // int64[8]    : layer-3 channel sums (atomic)
#define OFF_S2PART 10496     // int32[1024*16]: per-block layer-2 partial sums
#define OFF_Z2     76800     // int16[8192][144 px][16 oc]
#define OFF_Z3     37825792  // int16[8192][8 oc][16 px]
// total = 39922944 bytes (~39.9 MB)

// ---------------------------------------------------------------- K1: pack weights (block 0) + layer-1 window sums
__global__ __launch_bounds__(256) void k1_pack_tsum(const float* __restrict__ x,
                                                    const float* __restrict__ w1,
                                                    const float* __restrict__ w2,
                                                    const float* __restrict__ w3,
                                                    const float* __restrict__ wl,
                                                    const float* __restrict__ bl,
                                                    uint8_t* __restrict__ ws) {
  int* Ttot = (int*)(ws + OFF_TTOT);
  const int tid = threadIdx.x;

  // ---- block 0: pack all weights into ws ----
  if (blockIdx.x == 0) {
    uint32_t* W1R3 = (uint32_t*)(ws + OFF_W1R3);
    uint32_t* W2P  = (uint32_t*)(ws + OFF_W2P);
    uint32_t* W3P  = (uint32_t*)(ws + OFF_W3P);
    uint64_t* WLB  = (uint64_t*)(ws + OFF_WLB);
    float*    SBL  = (float*)(ws + OFF_SBL);
    // w1: (32,1,9,9). word i of oc holds rows 3i..3i+2 at bit offsets 0,9,18. bit=1 <=> w<0
    for (int e = tid; e < 96; e += 256) {
      int oc = e / 3, i = e % 3;
      uint32_t m = 0;
      for (int rr = 0; rr < 3; ++rr)
        for (int kw = 0; kw < 9; ++kw)
          if (w1[oc*81 + (3*i+rr)*9 + kw] < 0.f) m |= 1u << (rr*9 + kw);
      W1R3[e] = m;
    }
    // w2: (16,32,9,9) -> [och][kh][kw(pad 10)] uint2 over ic
    for (int e = tid; e < 648; e += 256) {
      int och = e / 81, k = e % 81;
      int kh = k / 9, kw = k % 9;
      uint32_t m0 = 0, m1 = 0;
      int oc0 = och*2;
      for (int ic = 0; ic < 32; ++ic) {
        if (w2[(oc0*32 + ic)*81 + k] < 0.f)     m0 |= 1u << ic;
        if (w2[((oc0+1)*32 + ic)*81 + k] < 0.f) m1 |= 1u << ic;
      }
      int idx = ((och*9 + kh)*10 + kw)*2;
      W2P[idx] = m0; W2P[idx+1] = m1;
    }
    for (int e = tid; e < 72; e += 256) {   // zero pad words kw=9
      int idx = (e*10 + 9)*2;
      W2P[idx] = 0; W2P[idx+1] = 0;
    }
    // w3: (8,16,9,9) -> [oc][kh][kw(pad 12)]
    for (int e = tid; e < 648; e += 256) {
      int oc = e / 81, k = e % 81;
      int kh = k / 9, kw = k % 9;
      uint32_t m = 0;
      for (int ic = 0; ic < 16; ++ic)
        if (w3[(oc*16 + ic)*81 + k] < 0.f) m |= 1u << ic;
      W3P[(oc*9 + kh)*12 + kw] = m;
    }
    for (int e = tid; e < 216; e += 256) {  // zero pads kw=9..11
      int row = e / 3, p = e % 3;
      W3P[row*12 + 9 + p] = 0;
    }
    // wl: (10,8,4,4) -> 128 bits per oc, bit j = ic*16 + (y*4+x)
    for (int e = tid; e < 20; e += 256) {
      int oc = e >> 1, word = e & 1;
      uint64_t m = 0;
      for (int b = 0; b < 64; ++b)
        if (wl[oc*128 + word*64 + b] < 0.f) m |= 1ull << b;
      WLB[e] = m;
    }
    if (tid < 10) SBL[tid] = (bl[tid] >= 0.f) ? 1.f : -1.f;
  }

  // ---- all blocks: layer-1 window sums for 32 images ----
  __shared__ uint32_t rowm[896];   // 32 imgs x 28 rows, bit c = (x<0)
  __shared__ int Tacc[81];
  if (tid < 81) Tacc[tid] = 0;
  __syncthreads();

  const int img0 = blockIdx.x * 32;
  #pragma unroll
  for (int it = 0; it < 4; ++it) {
    int R = tid + it*256;
    if (R < 896) {
      int il = R / 28, r = R % 28;
      const float4* xr = (const float4*)(x + (size_t)(img0 + il) * 784 + r * 28);
      uint32_t m = 0;
      #pragma unroll
      for (int j = 0; j < 7; ++j) {
        float4 v = xr[j];
        if (v.x < 0.f) m |= 1u << (j*4+0);
        if (v.y < 0.f) m |= 1u << (j*4+1);
        if (v.z < 0.f) m |= 1u << (j*4+2);
        if (v.w < 0.f) m |= 1u << (j*4+3);
      }
      rowm[R] = m;
    }
  }
  __syncthreads();

  // tasks: (il, kw) = 32*9 = 288. Sliding 20-row window of per-row neg counts.
  for (int T = tid; T < 288; T += 256) {
    int il = T / 9, kw = T % 9;
    int base = il * 28;
    int n9[9];
    int sum20 = 0;
    #pragma unroll
    for (int r = 0; r < 20; ++r) {
      int n = __popc((rowm[base + r] >> kw) & 0xFFFFFu);
      if (r < 9) n9[r] = n;
      sum20 += n;
    }
    atomicAdd(&Tacc[kw], 400 - 2*sum20);
    #pragma unroll
    for (int kh = 1; kh <= 8; ++kh) {
      int nadd = __popc((rowm[base + kh + 19] >> kw) & 0xFFFFFu);
      sum20 += nadd - n9[kh-1];
      atomicAdd(&Tacc[kh*9 + kw], 400 - 2*sum20);
    }
  }
  __syncthreads();
  if (tid < 81) atomicAdd(&Ttot[tid], Tacc[tid]);
}

// ---------------------------------------------------------------- K2: conv1 (recompute) + conv2
#define K2_IMGS 8
__global__ __launch_bounds__(256) void k2_conv12(const float* __restrict__ x,
                                                 uint8_t* __restrict__ ws) {
  const uint32_t* W1R3g = (const uint32_t*)(ws + OFF_W1R3);
  const uint32_t* W2Pg  = (const uint32_t*)(ws + OFF_W2P);
  const int* Ttot = (const int*)(ws + OFF_TTOT);
  int* S2P = (int*)(ws + OFF_S2PART);

  __shared__ uint32_t __attribute__((aligned(16))) rowm[K2_IMGS*28];
  __shared__ uint32_t __attribute__((aligned(16))) w1r3[96];
  __shared__ uint32_t __attribute__((aligned(16))) w2p[1440];
  __shared__ int tlds[81];
  __shared__ int t1s[32];
  __shared__ uint32_t __attribute__((aligned(16))) A1s[K2_IMGS*400];
  __shared__ int s2acc[16];

  const int tid = threadIdx.x;
  const int img0 = blockIdx.x * K2_IMGS;

  for (int e = tid; e < 96; e += 256)   w1r3[e] = W1R3g[e];
  for (int e = tid; e < 1440; e += 256) w2p[e]  = W2Pg[e];
  if (tid < 81) tlds[tid] = Ttot[tid];
  if (tid < 16) s2acc[tid] = 0;
  if (tid < K2_IMGS*28) {
    int il = tid / 28, rr = tid % 28;
    const float4* xr = (const float4*)(x + (size_t)(img0 + il) * 784 + rr * 28);
    uint32_t m = 0;
    #pragma unroll
    for (int j = 0; j < 7; ++j) {
      float4 v = xr[j];
      if (v.x < 0.f) m |= 1u << (j*4+0);
      if (v.y < 0.f) m |= 1u << (j*4+1);
      if (v.z < 0.f) m |= 1u << (j*4+2);
      if (v.w < 0.f) m |= 1u << (j*4+3);
    }
    rowm[tid] = m;
  }
  __syncthreads();

  // layer-1 thresholds (odd parity): t1 = smallest odd integer >= S1/N1
  if (tid < 32) {
    long long S = 0;
    for (int kh = 0; kh < 9; ++kh)
      for (int kw = 0; kw < 9; ++kw) {
        int bit = (w1r3[tid*3 + kh/3] >> ((kh%3)*9 + kw)) & 1;
        S += (long long)(1 - 2*bit) * tlds[kh*9 + kw];
      }
    const long long N1 = (long long)BATCH * 400;
    long long q = S / N1, rr = S % N1;
    long long t = q + (rr > 0 ? 1 : 0);
    if ((t & 1) == 0) t += 1;
    t1s[tid] = (int)t;
  }
  __syncthreads();

  // conv1 + binarize -> A1s. Task = (il, oh, 5-ow group): 8*20*4 = 640 tasks.
  for (int G = tid; G < K2_IMGS*80; G += 256) {
    int il = G / 80, rem = G - il*80;
    int oh = rem >> 2, ow0 = (rem & 3) * 5;
    uint32_t R[9];
    #pragma unroll
    for (int i = 0; i < 9; ++i) R[i] = rowm[il*28 + oh + i];
    uint32_t win[5][3];
    #pragma unroll
    for (int j = 0; j < 5; ++j) {
      int ow = ow0 + j;
      #pragma unroll
      for (int i = 0; i < 3; ++i) {
        uint32_t b0 = (R[3*i]   >> ow) & 0x1FFu;
        uint32_t b1 = (R[3*i+1] >> ow) & 0x1FFu;
        uint32_t b2 = (R[3*i+2] >> ow) & 0x1FFu;
        win[j][i] = b0 | (b1 << 9) | (b2 << 18);
      }
    }
    uint32_t mask[5] = {0,0,0,0,0};
    #pragma unroll
    for (int ocg = 0; ocg < 4; ++ocg) {
      const uint4* wp = (const uint4*)&w1r3[ocg*24];
      uint32_t wr[24];
      #pragma unroll
      for (int q = 0; q < 6; ++q) {
        uint4 v = wp[q];
        wr[q*4+0]=v.x; wr[q*4+1]=v.y; wr[q*4+2]=v.z; wr[q*4+3]=v.w;
      }
      #pragma unroll
      for (int o8 = 0; o8 < 8; ++o8) {
        int oc = ocg*8 + o8;
        int t = t1s[oc];
        #pragma unroll
        for (int j = 0; j < 5; ++j) {
          int mm = __popc(win[j][0] ^ wr[o8*3])
                 + __popc(win[j][1] ^ wr[o8*3+1])
                 + __popc(win[j][2] ^ wr[o8*3+2]);
          mask[j] |= (uint32_t)((81 - 2*mm) < t) << oc;
        }
      }
    }
    #pragma unroll
    for (int j = 0; j < 5; ++j) A1s[il*400 + oh*20 + ow0 + j] = mask[j];
  }
  __syncthreads();

  // conv2: task = (il, oy, oc-pair): 8*12*8 = 768 tasks, 3 per thread.
  // och = tid&7 invariant per thread -> weights indexed by och only.
  uint32_t* Z2w = (uint32_t*)(ws + OFF_Z2);
  const int och = tid & 7, oc0 = och << 1;
  int sl0 = 0, sl1 = 0;
  for (int r = 0; r < 3; ++r) {
    int G = tid + r*256;
    int il = G / 96, rem = G - il*96;
    int oy = rem >> 3;
    const uint32_t* A = &A1s[il*400 + oy*20];
    int acc0[12], acc1[12];
    #pragma unroll
    for (int p = 0; p < 12; ++p) { acc0[p] = 0; acc1[p] = 0; }
    for (int kh = 0; kh < 9; ++kh) {
      const uint4* ar = (const uint4*)(A + kh*20);
      uint32_t a[20];
      #pragma unroll
      for (int q = 0; q < 5; ++q) {
        uint4 v = ar[q];
        a[q*4+0]=v.x; a[q*4+1]=v.y; a[q*4+2]=v.z; a[q*4+3]=v.w;
      }
      const uint4* wp4 = (const uint4*)&w2p[(och*9 + kh)*20];
      uint32_t wbuf[20];
      #pragma unroll
      for (int q = 0; q < 5; ++q) {
        uint4 v = wp4[q];
        wbuf[q*4+0]=v.x; wbuf[q*4+1]=v.y; wbuf[q*4+2]=v.z; wbuf[q*4+3]=v.w;
      }
      #pragma unroll
      for (int kw = 0; kw < 9; ++kw) {
        uint32_t w0 = wbuf[2*kw], w1v = wbuf[2*kw+1];
        #pragma unroll
        for (int px = 0; px < 12; ++px) {
          acc0[px] += __popc(a[kw+px] ^ w0);
          acc1[px] += __popc(a[kw+px] ^ w1v);
        }
      }
    }
    // store Z2 in [img][px][oc] layout: word = z(oc0) | z(oc1)<<16
    size_t wbase = (size_t)(img0+il)*1152 + (size_t)oy*96 + och;
    #pragma unroll
    for (int px = 0; px < 12; ++px) {
      int z0 = 2592 - 2*acc0[px], z1v = 2592 - 2*acc1[px];
      sl0 += z0; sl1 += z1v;
      Z2w[wbase + px*8] = (uint32_t)(uint16_t)(int16_t)z0
                        | ((uint32_t)(uint16_t)(int16_t)z1v << 16);
    }
  }
  atomicAdd(&s2acc[oc0],   sl0);
  atomicAdd(&s2acc[oc0+1], sl1);
  __syncthreads();
  if (tid < 16) S2P[blockIdx.x*16 + tid] = s2acc[tid];
}

// ---------------------------------------------------------------- K3: t2-reduce + binarize + conv3
__global__ __launch_bounds__(256) void k3_conv3(uint8_t* __restrict__ ws) {
  const int* S2P = (const int*)(ws + OFF_S2PART);
  const uint32_t* W3Pg = (const uint32_t*)(ws + OFF_W3P);
  const uint32_t* Z2w = (const uint32_t*)(ws + OFF_Z2);
  uint32_t* Z3w = (uint32_t*)(ws + OFF_Z3);
  unsigned long long* S3 = (unsigned long long*)(ws + OFF_S3);

  __shared__ uint32_t __attribute__((aligned(16))) w3p[864];
  __shared__ int part[256];
  __shared__ int t2s[16];
  __shared__ uint32_t __attribute__((aligned(16))) A2[32*144];
  __shared__ int s3acc[8];

  const int tid = threadIdx.x;
  const int img0 = blockIdx.x * 32;

  // phase 0: redundant t2 reduction from S2P (64 KB, L2-resident after first block)
  {
    int c = tid & 15, g = tid >> 4;
    int s = 0;
    for (int j = 0; j < 64; ++j) s += S2P[(g + 16*j)*16 + c];
    part[tid] = s;
  }
  for (int e = tid; e < 864; e += 256) w3p[e] = W3Pg[e];
  if (tid < 8) s3acc[tid] = 0;
  __syncthreads();
  if (tid < 16) {
    long long S = 0;
    #pragma unroll
    for (int g = 0; g < 16; ++g) S += (long long)part[g*16 + tid];
    const long long N2 = (long long)BATCH * 144;
    long long q = S / N2, r = S % N2;
    long long t = q + (r > 0 ? 1 : 0);
    if (t & 1) t += 1;   // z2 is even
    t2s[tid] = (int)t;
  }
  __syncthreads();

  // phase 1: binarize z2 -> A2 bit masks. 32 imgs x 144 px, coalesced 32B/px reads.
  #pragma unroll
  for (int j = 0; j < 18; ++j) {
    int idx = tid + j*256;           // 0..4607
    const uint4* zp = (const uint4*)&Z2w[(size_t)(img0 + idx/144)*1152 + (size_t)(idx%144)*8];
    uint4 v0 = zp[0], v1 = zp[1];
    uint32_t zz[8] = {v0.x,v0.y,v0.z,v0.w, v1.x,v1.y,v1.z,v1.w};
    uint32_t m = 0;
    #pragma unroll
    for (int i = 0; i < 8; ++i) {
      int zlo = (int)(short)(zz[i] & 0xFFFFu);
      int zhi = (int)zz[i] >> 16;
      m |= (uint32_t)(zlo < t2s[2*i])   << (2*i);
      m |= (uint32_t)(zhi < t2s[2*i+1]) << (2*i+1);
    }
    A2[idx] = m;
  }
  __syncthreads();

  // phase 2: conv3. Task = (il, oc) = 32*8 = 256, one per thread.
  const int il = tid >> 3, oc = tid & 7;
  int acc[16];
  #pragma unroll
  for (int i = 0; i < 16; ++i) acc[i] = 0;
  #pragma unroll
  for (int r = 0; r < 12; ++r) {
    const uint4* ar = (const uint4*)&A2[il*144 + r*12];
    uint4 v0 = ar[0], v1 = ar[1], v2 = ar[2];
    uint32_t a[12] = {v0.x,v0.y,v0.z,v0.w, v1.x,v1.y,v1.z,v1.w, v2.x,v2.y,v2.z,v2.w};
    #pragma unroll
    for (int oy = 0; oy < 4; ++oy) {
      if (r - oy >= 0 && r - oy <= 8) {
        int kh = r - oy;
        const uint4* wr = (const uint4*)&w3p[(oc*9 + kh)*12];
        uint4 w0 = wr[0], w1v = wr[1], w2v = wr[2];
        uint32_t w[9] = {w0.x,w0.y,w0.z,w0.w, w1v.x,w1v.y,w1v.z,w1v.w, w2v.x};
        #pragma unroll
        for (int ox = 0; ox < 4; ++ox) {
          int m = 0;
          #pragma unroll
          for (int kw = 0; kw < 9; ++kw) m += __popc(a[ox+kw] ^ w[kw]);
          acc[oy*4+ox] += m;
        }
      }
    }
  }
  // z3 = 1296 - 2*mism; store [img][oc][16 px] int16; sum for channel means
  int ssum = 0;
  uint32_t packed[8];
  #pragma unroll
  for (int h = 0; h < 8; ++h) {
    int za = 1296 - 2*acc[2*h], zb = 1296 - 2*acc[2*h+1];
    ssum += za + zb;
    packed[h] = (uint32_t)(uint16_t)(int16_t)za | ((uint32_t)(uint16_t)(int16_t)zb << 16);
  }
  uint4* zp = (uint4*)&Z3w[(size_t)(img0 + il)*64 + oc*8];
  zp[0] = make_uint4(packed[0], packed[1], packed[2], packed[3]);
  zp[1] = make_uint4(packed[4], packed[5], packed[6], packed[7]);
  atomicAdd(&s3acc[oc], ssum);
  __syncthreads();
  if (tid < 8)
    atomicAdd(&S3[tid], (unsigned long long)(long long)s3acc[tid]);
}

// ---------------------------------------------------------------- K4: conv4 + bias -> out
__global__ __launch_bounds__(256) void k4_final(uint8_t* __restrict__ ws,
                                                float* __restrict__ out) {
  const uint32_t* Z3w = (const uint32_t*)(ws + OFF_Z3);
  const long long* S3 = (const long long*)(ws + OFF_S3);
  const uint64_t* WLBg = (const uint64_t*)(ws + OFF_WLB);
  const float* SBLg = (const float*)(ws + OFF_SBL);
  __shared__ int t3[8];
  __shared__ uint64_t wlb[20];
  __shared__ float sbl[10];
  const int tid = threadIdx.x;
  if (tid < 8) {
    long long S = S3[tid];
    const long long N3 = (long long)BATCH * 16;
    long long q = S / N3, r = S % N3;
    long long t = q + (r > 0 ? 1 : 0);
    if (t & 1) t += 1;   // z3 is even
    t3[tid] = (int)t;
  }
  if (tid < 20) wlb[tid] = WLBg[tid];
  if (tid < 10) sbl[tid] = SBLg[tid];
  __syncthreads();
  int img = blockIdx.x * 256 + tid;
  const uint4* zp = (const uint4*)&Z3w[(size_t)img * 64];
  uint32_t zz[64];                      // FIX (R4 bug): full 64 words = 8 oc x 16 px
  #pragma unroll
  for (int q = 0; q < 16; ++q) {
    uint4 v = zp[q];
    zz[q*4+0]=v.x; zz[q*4+1]=v.y; zz[q*4+2]=v.z; zz[q*4+3]=v.w;
  }
  uint64_t a0 = 0, a1 = 0;
  #pragma unroll
  for (int j = 0; j < 64; ++j) {
    int z = (j & 1) ? ((int)zz[j>>1] >> 16) : (int)(short)(zz[j>>1] & 0xFFFFu);
    a0 |= (uint64_t)(z < t3[j >> 4]) << j;
  }
  #pragma unroll
  for (int j = 0; j < 64; ++j) {
    int z = (j & 1) ? ((int)zz[32 + (j>>1)] >> 16) : (int)(short)(zz[32 + (j>>1)] & 0xFFFFu);
    a1 |= (uint64_t)(z < t3[(64 + j) >> 4]) << j;
  }
  #pragma unroll
  for (int oc = 0; oc < 10; ++oc) {
    int mism = __popcll(a0 ^ wlb[oc*2]) + __popcll(a1 ^ wlb[oc*2 + 1]);
    out[(size_t)img*10 + oc] = (float)(128 - 2*mism) + sbl[oc];
  }
}

// ----------------------------------------------------------------
extern "C" void kernel_launch(void* const* d_in, const int* in_sizes, int n_in,
                              void* d_out, int out_size, void* d_ws, size_t ws_size,
                              hipStream_t stream) {
  (void)in_sizes; (void)n_in; (void)out_size; (void)ws_size;
  const float* x  = (const float*)d_in[0];
  const float* w1 = (const float*)d_in[1];
  // d_in[2] = b1, d_in[4] = b2, d_in[6] = b3: biases cancel under BN -> unused
  const float* w2 = (const float*)d_in[3];
  const float* w3 = (const float*)d_in[5];
  const float* wl = (const float*)d_in[7];
  const float* bl = (const float*)d_in[8];
  uint8_t* ws = (uint8_t*)d_ws;
  float* out = (float*)d_out;

  // zero TTOT + S3 accumulators (ws is poisoned 0xAA each call)
  hipMemsetAsync(ws + OFF_TTOT, 0, 400, stream);
  k1_pack_tsum<<<256, 256, 0, stream>>>(x, w1, w2, w3, wl, bl, ws);
  k2_conv12<<<1024, 256, 0, stream>>>(x, ws);
  k3_conv3<<<256, 256, 0, stream>>>(ws);
  k4_final<<<32, 256, 0, stream>>>(ws, out);
}